// Round 8
// baseline (1322.338 us; speedup 1.0000x reference)
//
#include <hip/hip_runtime.h>
#include <math.h>
#include <stdint.h>

#define CC 512
#define NN 4096
#define BB 4

typedef _Float16 f16;
typedef _Float16 f16x8 __attribute__((ext_vector_type(8)));
typedef _Float16 f16x4 __attribute__((ext_vector_type(4)));
typedef float f32x4 __attribute__((ext_vector_type(4)));

// ---------- async global->LDS 16B ----------
__device__ __forceinline__ void gload_lds16(const void* g, void* l) {
    __builtin_amdgcn_global_load_lds(
        (const __attribute__((address_space(1))) void*)g,
        (__attribute__((address_space(3))) void*)l, 16, 0, 0);
}

// Stage ROWS rows x 64 f16 from K-major global into linear LDS; source pre-swizzled.
template<int ROWS>
__device__ __forceinline__ void stage_tile(const f16* __restrict__ g, int stride_e,
                                           f16* lds, int wid, int lane) {
    constexpr int ITERS = ROWS * 8 / 64 / 4;   // 4 waves
    #pragma unroll
    for (int it = 0; it < ITERS; ++it) {
        int flatbase = (wid * ITERS + it) * 64;
        f16* dst = lds + flatbase * 8;
        int flat = flatbase + lane;
        int r = flat >> 3, c = flat & 7;
        const f16* src = g + (size_t)r * stride_e + ((c ^ (r & 7)) << 3);
        gload_lds16(src, dst);
    }
}

__device__ __forceinline__ f16x8 frag_ld(const f16* lds, int r, int ch) {
    return *(const f16x8*)(lds + r * 64 + ((ch ^ (r & 7)) << 3));
}

#define MFMA16(a, b, c) __builtin_amdgcn_mfma_f32_16x16x32_f16((a), (b), (c), 0, 0, 0)

// ---------- DPP row_ror reductions over 16-lane rows (VALU only, no LDS pipe) ----------
template<int N>
__device__ __forceinline__ float ror16(float x) {
    return __int_as_float(__builtin_amdgcn_update_dpp(
        0, __float_as_int(x), 0x120 + N, 0xF, 0xF, true));
}
__device__ __forceinline__ f32x4 rmax16(f32x4 v) {
    #pragma unroll
    for (int q = 0; q < 4; ++q) {
        float x = v[q];
        x = fmaxf(x, ror16<1>(x));
        x = fmaxf(x, ror16<2>(x));
        x = fmaxf(x, ror16<4>(x));
        x = fmaxf(x, ror16<8>(x));
        v[q] = x;
    }
    return v;
}
__device__ __forceinline__ f32x4 rsum16(f32x4 v) {
    #pragma unroll
    for (int q = 0; q < 4; ++q) {
        float x = v[q];
        x += ror16<1>(x);
        x += ror16<2>(x);
        x += ror16<4>(x);
        x += ror16<8>(x);
        v[q] = x;
    }
    return v;
}

// ---------------- W conversion ----------------
__global__ __launch_bounds__(256) void wcvt_k(const float* __restrict__ Wb,
                                              const float* __restrict__ Wc,
                                              const float* __restrict__ Wd,
                                              f16* __restrict__ W16) {
    int i = blockIdx.x * 256 + threadIdx.x;
    int idx = i * 4;
    int m = idx >> 18;
    int off = idx & 262143;
    const float* src = (m == 0) ? Wb : (m == 1) ? Wc : Wd;
    f32x4 v = *(const f32x4*)(src + off);
    f16x4 h = { (f16)v[0], (f16)v[1], (f16)v[2], (f16)v[3] };
    *(f16x4*)(W16 + idx) = h;
}

// ---------------- proj (all batches): O = W @ x ----------------
__global__ __launch_bounds__(256) void proj_k(const float* __restrict__ x,
                                              const f16* __restrict__ W16,
                                              f16* __restrict__ Bt, f16* __restrict__ Ct,
                                              f16* __restrict__ Dm) {
    const int wsel = blockIdx.z % 3;
    const int b = blockIdx.z / 3;
    const f16* __restrict__ W = W16 + (size_t)wsel * CC * CC;
    const float* __restrict__ X = x + (size_t)b * CC * NN;
    const size_t p16 = (size_t)CC * NN;
    const int o0 = blockIdx.y * 128, n0 = blockIdx.x * 128;

    __shared__ __align__(16) char smraw[34816];
    f16* As = (f16*)smraw;
    f16* Bs = As + 128 * 64;
    f16* T  = (f16*)smraw;

    const int t = threadIdx.x;
    const int wid = t >> 6, lane = t & 63;
    const int wr = wid >> 1, wc = wid & 1;

    f32x4 acc[4][4] = {};
    const int cg = t & 7;
    const int n4 = ((t >> 3) & 31) * 4;

    for (int kc = 0; kc < CC; kc += 64) {
        __syncthreads();
        stage_tile<128>(W + (size_t)o0 * CC + kc, CC, As, wid, lane);
        f32x4 v[8];
        #pragma unroll
        for (int i = 0; i < 8; ++i)
            v[i] = *(const f32x4*)(X + (size_t)(kc + cg * 8 + i) * NN + n0 + n4);
        #pragma unroll
        for (int j = 0; j < 4; ++j) {
            f16x8 h = { (f16)v[0][j], (f16)v[1][j], (f16)v[2][j], (f16)v[3][j],
                        (f16)v[4][j], (f16)v[5][j], (f16)v[6][j], (f16)v[7][j] };
            int r = n4 + j;
            *(f16x8*)(Bs + r * 64 + ((cg ^ (r & 7)) << 3)) = h;
        }
        __syncthreads();
        #pragma unroll
        for (int ks = 0; ks < 2; ++ks) {
            int ch = ks * 4 + (lane >> 4);
            f16x8 a[4], bb[4];
            #pragma unroll
            for (int i = 0; i < 4; ++i) a[i]  = frag_ld(As, wr * 64 + i * 16 + (lane & 15), ch);
            #pragma unroll
            for (int j = 0; j < 4; ++j) bb[j] = frag_ld(Bs, wc * 64 + j * 16 + (lane & 15), ch);
            #pragma unroll
            for (int i = 0; i < 4; ++i)
                #pragma unroll
                for (int j = 0; j < 4; ++j)
                    acc[i][j] = MFMA16(a[i], bb[j], acc[i][j]);
        }
    }

    __syncthreads();
    if (wsel < 2) {
        #pragma unroll
        for (int i = 0; i < 4; ++i)
            #pragma unroll
            for (int j = 0; j < 4; ++j) {
                int n_l = wc * 64 + j * 16 + (lane & 15);
                int o_l = wr * 64 + i * 16 + (lane >> 4) * 4;
                f16x4 h = { (f16)acc[i][j][0], (f16)acc[i][j][1], (f16)acc[i][j][2], (f16)acc[i][j][3] };
                *(f16x4*)(T + n_l * 136 + o_l) = h;
            }
        __syncthreads();
        f16* __restrict__ dst = ((wsel == 0) ? Bt : Ct) + (size_t)b * p16;
        int n = t & 127;
        #pragma unroll
        for (int it = 0; it < 8; ++it) {
            int ch8 = (t >> 7) * 8 + it;
            f16x8 h = *(f16x8*)(T + n * 136 + ch8 * 8);
            *(f16x8*)(dst + (size_t)(n0 + n) * CC + o0 + ch8 * 8) = h;
        }
    } else {
        #pragma unroll
        for (int i = 0; i < 4; ++i)
            #pragma unroll
            for (int j = 0; j < 4; ++j) {
                int n_l = wc * 64 + j * 16 + (lane & 15);
                #pragma unroll
                for (int q = 0; q < 4; ++q) {
                    int o_l = wr * 64 + i * 16 + (lane >> 4) * 4 + q;
                    T[o_l * 136 + n_l] = (f16)acc[i][j][q];
                }
            }
        __syncthreads();
        f16* __restrict__ dst = Dm + (size_t)b * p16;
        int o = t & 127;
        #pragma unroll
        for (int it = 0; it < 8; ++it) {
            int ch8 = (t >> 7) * 8 + it;
            f16x8 h = *(f16x8*)(T + o * 136 + ch8 * 8);
            *(f16x8*)(dst + (size_t)(o0 + o) * NN + n0 + ch8 * 8) = h;
        }
    }
}

// ---------- flash staging helpers ----------
__device__ __forceinline__ void stage_Ct(const f16* __restrict__ Ctb, f16* CtS,
                                         int m0, int wid, int lane) {
    #pragma unroll
    for (int it = 0; it < 8; ++it) {
        int r = wid * 8 + it;
        f16* dst = CtS + r * 512;              // wave-uniform base
        const f16* src = Ctb + (size_t)(m0 + r) * CC + ((lane ^ (r & 7)) << 3);
        gload_lds16(src, dst);
    }
}
__device__ __forceinline__ void stage_Dt(const f16* __restrict__ Dmb, f16* DtS,
                                         int m0, int wid, int lane) {
    #pragma unroll
    for (int it = 0; it < 8; ++it) {
        int flatbase = (wid * 8 + it) * 64;
        f16* dst = DtS + flatbase * 8;
        int flat = flatbase + lane;
        int r = flat >> 3, c = flat & 7;
        const f16* src = Dmb + (size_t)r * NN + m0 + ((c ^ (r & 7)) << 3);
        gload_lds16(src, dst);
    }
}

// ---------------- fused flash attention ----------------
// Round-4 geometry (register-safe at the 128-VGPR cap: Q[16]+O[16]).
// Round-7 pipelined staging. New this round: DPP row_ror reductions (no LDS-pipe
// bpermute) + defer-rescale (skip O-scale while row max grows <= 8).
__global__ __launch_bounds__(512)
void flash_k(
    const float* __restrict__ x, const float* __restrict__ gamma_p,
    const f16* __restrict__ Bt, const f16* __restrict__ Ct,
    const f16* __restrict__ Dm, float* __restrict__ out)
{
    __shared__ __align__(16) char sm[141312];
    f16* CtS = (f16*)sm;                       // [64 m][512 K]   65536 B
    f16* DtS = (f16*)(sm + 65536);             // [512 c][64 m]   65536 B
    f16* PS  = (f16*)(sm + 131072);            // [64 n][64 m]     8192 B
    float* mxp = (float*)(sm + 139264);        // [2][64]
    float* lp  = (float*)(sm + 140288);        // [2][64]

    // XCD-pair swizzle: 256 blocks; xcd = bx&7 -> batch (xcd>>1), tile-half (xcd&1)
    const int bx = blockIdx.x;
    const int j8 = bx & 7;
    const int b = j8 >> 1;
    const int n0 = ((bx >> 3) + (j8 & 1) * 32) * 64;

    const size_t p16 = (size_t)CC * NN;
    const f16* __restrict__ Btb = Bt + (size_t)b * p16;   // [n][c]
    const f16* __restrict__ Ctb = Ct + (size_t)b * p16;   // [m][c]
    const f16* __restrict__ Dmb = Dm + (size_t)b * p16;   // [c][m]

    const int t = threadIdx.x;
    const int wid = t >> 6, lane = t & 63;
    const int wr = wid >> 1, w1 = wid & 1;
    const int l15 = lane & 15, g = lane >> 4;

    // Q fragments: rows wr*16+l15, K chunk s*32 + g*8
    f16x8 Q[16];
    {
        const f16* qrow = Btb + (size_t)(n0 + wr * 16 + l15) * CC + g * 8;
        #pragma unroll
        for (int s = 0; s < 16; ++s) Q[s] = *(const f16x8*)(qrow + s * 32);
    }

    f32x4 O[16];
    #pragma unroll
    for (int i = 0; i < 16; ++i) O[i] = (f32x4)(0.f);
    f32x4 m_run = (f32x4)(-INFINITY);
    f32x4 l_run = (f32x4)(0.f);

    // prologue: stage Ct(0), publish
    stage_Ct(Ctb, CtS, 0, wid, lane);
    __syncthreads();

    for (int m0 = 0; m0 < NN; m0 += 64) {
        // issue Dt(m0) now; it lands under QK and is published at bar1
        stage_Dt(Dmb, DtS, m0, wid, lane);

        // QK^T: wave tile 16n x 32m (frags f=0,1), reading CtS(m0)
        f32x4 S0 = (f32x4)(0.f), S1 = (f32x4)(0.f);
        __builtin_amdgcn_s_setprio(1);
        #pragma unroll
        for (int s = 0; s < 16; ++s) {
            int ch = s * 4 + g;
            int mr0 = w1 * 32 + l15;
            int mr1 = mr0 + 16;
            f16x8 b0 = *(const f16x8*)(CtS + mr0 * 512 + (((ch ^ (mr0 & 7)) & 63) << 3));
            f16x8 b1 = *(const f16x8*)(CtS + mr1 * 512 + (((ch ^ (mr1 & 7)) & 63) << 3));
            S0 = MFMA16(Q[s], b0, S0);
            S1 = MFMA16(Q[s], b1, S1);
        }
        __builtin_amdgcn_s_setprio(0);
        // wave-tile row max (rows wr*16+g*4+q) via DPP, exchange across m-halves
        f32x4 tm;
        #pragma unroll
        for (int q = 0; q < 4; ++q) tm[q] = fmaxf(S0[q], S1[q]);
        tm = rmax16(tm);
        if (l15 == 0) *(f32x4*)(mxp + w1 * 64 + wr * 16 + g * 4) = tm;
        __syncthreads();                       // bar1: mxp + DtS(m0) published
        f32x4 t0 = *(const f32x4*)(mxp + wr * 16 + g * 4);
        f32x4 t1 = *(const f32x4*)(mxp + 64 + wr * 16 + g * 4);
        // defer-rescale: only bump m_run when the max grew by > 8
        f32x4 mx4, scl, p0, p1, ps;
        bool grow = false;
        #pragma unroll
        for (int q = 0; q < 4; ++q) {
            mx4[q] = fmaxf(t0[q], t1[q]);
            grow = grow || (mx4[q] > m_run[q] + 8.0f);
        }
        const bool doRescale = __any((int)grow);
        if (doRescale) {
            #pragma unroll
            for (int q = 0; q < 4; ++q) {
                float mnew = fmaxf(m_run[q], mx4[q]);
                scl[q] = __expf(m_run[q] - mnew);
                m_run[q] = mnew;
            }
        }
        #pragma unroll
        for (int q = 0; q < 4; ++q) {
            p0[q] = __expf(S0[q] - m_run[q]);
            p1[q] = __expf(S1[q] - m_run[q]);
            ps[q] = p0[q] + p1[q];
        }
        ps = rsum16(ps);
        if (l15 == 0) *(f32x4*)(lp + w1 * 64 + wr * 16 + g * 4) = ps;
        // write P (f16) swizzled
        #pragma unroll
        for (int q = 0; q < 4; ++q) {
            int row = wr * 16 + g * 4 + q;
            int c0 = w1 * 32 + l15;
            int c1 = c0 + 16;
            PS[row * 64 + ((((c0 >> 3) ^ (row & 7)) << 3) | (c0 & 7))] = (f16)p0[q];
            PS[row * 64 + ((((c1 >> 3) ^ (row & 7)) << 3) | (c1 & 7))] = (f16)p1[q];
        }
        __syncthreads();                       // bar2: P + lp published

        // issue Ct(m0+64) now; it lands under PV and is published at bar3
        if (m0 + 64 < NN) stage_Ct(Ctb, CtS, m0 + 64, wid, lane);

        f32x4 lp0 = *(const f32x4*)(lp + wr * 16 + g * 4);
        f32x4 lp1 = *(const f32x4*)(lp + 64 + wr * 16 + g * 4);
        if (doRescale) {
            #pragma unroll
            for (int q = 0; q < 4; ++q) l_run[q] = l_run[q] * scl[q] + lp0[q] + lp1[q];
            #pragma unroll
            for (int i = 0; i < 16; ++i)
                #pragma unroll
                for (int q = 0; q < 4; ++q) O[i][q] *= scl[q];
        } else {
            #pragma unroll
            for (int q = 0; q < 4; ++q) l_run[q] += lp0[q] + lp1[q];
        }
        // PV: wave tile 16n x 256c (w1 = c-half)
        int prow = wr * 16 + l15;
        f16x8 pa0 = *(const f16x8*)(PS + prow * 64 + (((g ^ (prow & 7)) & 7) << 3));
        f16x8 pa1 = *(const f16x8*)(PS + prow * 64 + ((((4 + g) ^ (prow & 7)) & 7) << 3));
        __builtin_amdgcn_s_setprio(1);
        #pragma unroll
        for (int jj = 0; jj < 16; ++jj) {
            int crow = w1 * 256 + jj * 16 + l15;
            f16x8 d0 = *(const f16x8*)(DtS + crow * 64 + (((g ^ (crow & 7)) & 7) << 3));
            f16x8 d1 = *(const f16x8*)(DtS + crow * 64 + ((((4 + g) ^ (crow & 7)) & 7) << 3));
            O[jj] = MFMA16(pa0, d0, O[jj]);
            O[jj] = MFMA16(pa1, d1, O[jj]);
        }
        __builtin_amdgcn_s_setprio(0);
        __syncthreads();                       // bar3: CtS(next) published; PS consumed
    }

    // ---------------- epilogue: out[c][n] = gamma*O/l + x ----------------
    const float gam = gamma_p[0];
    f32x4 inv;
    #pragma unroll
    for (int q = 0; q < 4; ++q) inv[q] = gam / l_run[q];
    float* T = (float*)sm;                     // [512][68] f32 = 139264 B
    #pragma unroll
    for (int jj = 0; jj < 16; ++jj) {
        int crow = w1 * 256 + jj * 16 + l15;
        f32x4 v;
        #pragma unroll
        for (int q = 0; q < 4; ++q) v[q] = O[jj][q] * inv[q];
        *(f32x4*)(T + crow * 68 + wr * 16 + g * 4) = v;
    }
    __syncthreads();
    const float* __restrict__ xb = x + (size_t)b * CC * NN;
    float* __restrict__ ob = out + (size_t)b * CC * NN;
    #pragma unroll
    for (int it = 0; it < 16; ++it) {
        int c = (t >> 4) + it * 32;
        int n4 = (t & 15) * 4;
        f32x4 v = *(const f32x4*)(T + c * 68 + n4);
        f32x4 xv = *(const f32x4*)(xb + (size_t)c * NN + n0 + n4);
        #pragma unroll
        for (int q = 0; q < 4; ++q) v[q] += xv[q];
        *(f32x4*)(ob + (size_t)c * NN + n0 + n4) = v;
    }
}

extern "C" void kernel_launch(void* const* d_in, const int* in_sizes, int n_in,
                              void* d_out, int out_size, void* d_ws, size_t ws_size,
                              hipStream_t stream) {
    const float* x  = (const float*)d_in[0];
    const float* Wb = (const float*)d_in[1];
    const float* Wc = (const float*)d_in[2];
    const float* Wd = (const float*)d_in[3];
    const float* gm = (const float*)d_in[4];
    float* out = (float*)d_out;
    char* ws = (char*)d_ws;

    // ws: W16 1.5MB | Bt 16MB | Ct 16MB | Dm 16MB  (~49.5MB)
    f16* W16 = (f16*)(ws);
    f16* Bt  = (f16*)(ws + 1572864);
    f16* Ct  = (f16*)(ws + 1572864 + 16777216);
    f16* Dm  = (f16*)(ws + 1572864 + 2 * 16777216);

    wcvt_k<<<dim3(768), 256, 0, stream>>>(Wb, Wc, Wd, W16);
    proj_k<<<dim3(32, 4, 12), 256, 0, stream>>>(x, W16, Bt, Ct, Dm);
    flash_k<<<dim3(256), 512, 0, stream>>>(x, gm, Bt, Ct, Dm, out);
}

// Round 9
// 729.285 us; speedup vs baseline: 1.8132x; 1.8132x over previous
//
#include <hip/hip_runtime.h>
#include <math.h>
#include <stdint.h>

#define CC 512
#define NN 4096
#define BB 4

typedef _Float16 f16;
typedef _Float16 f16x8 __attribute__((ext_vector_type(8)));
typedef _Float16 f16x4 __attribute__((ext_vector_type(4)));
typedef float f32x4 __attribute__((ext_vector_type(4)));

// ---------- async global->LDS 16B ----------
__device__ __forceinline__ void gload_lds16(const void* g, void* l) {
    __builtin_amdgcn_global_load_lds(
        (const __attribute__((address_space(1))) void*)g,
        (__attribute__((address_space(3))) void*)l, 16, 0, 0);
}

// Stage ROWS rows x 64 f16 from K-major global into linear LDS; source pre-swizzled.
template<int ROWS>
__device__ __forceinline__ void stage_tile(const f16* __restrict__ g, int stride_e,
                                           f16* lds, int wid, int lane) {
    constexpr int ITERS = ROWS * 8 / 64 / 4;   // 4 waves
    #pragma unroll
    for (int it = 0; it < ITERS; ++it) {
        int flatbase = (wid * ITERS + it) * 64;
        f16* dst = lds + flatbase * 8;
        int flat = flatbase + lane;
        int r = flat >> 3, c = flat & 7;
        const f16* src = g + (size_t)r * stride_e + ((c ^ (r & 7)) << 3);
        gload_lds16(src, dst);
    }
}

__device__ __forceinline__ f16x8 frag_ld(const f16* lds, int r, int ch) {
    return *(const f16x8*)(lds + r * 64 + ((ch ^ (r & 7)) << 3));
}

#define MFMA16(a, b, c) __builtin_amdgcn_mfma_f32_16x16x32_f16((a), (b), (c), 0, 0, 0)

// ---------- DPP row_ror reductions over 16-lane rows (VALU only, register-neutral) ----------
template<int N>
__device__ __forceinline__ float ror16(float x) {
    return __int_as_float(__builtin_amdgcn_update_dpp(
        0, __float_as_int(x), 0x120 + N, 0xF, 0xF, true));
}
__device__ __forceinline__ f32x4 rmax16(f32x4 v) {
    #pragma unroll
    for (int q = 0; q < 4; ++q) {
        float x = v[q];
        x = fmaxf(x, ror16<1>(x));
        x = fmaxf(x, ror16<2>(x));
        x = fmaxf(x, ror16<4>(x));
        x = fmaxf(x, ror16<8>(x));
        v[q] = x;
    }
    return v;
}
__device__ __forceinline__ f32x4 rsum16(f32x4 v) {
    #pragma unroll
    for (int q = 0; q < 4; ++q) {
        float x = v[q];
        x += ror16<1>(x);
        x += ror16<2>(x);
        x += ror16<4>(x);
        x += ror16<8>(x);
        v[q] = x;
    }
    return v;
}

// ---------------- W conversion ----------------
__global__ __launch_bounds__(256) void wcvt_k(const float* __restrict__ Wb,
                                              const float* __restrict__ Wc,
                                              const float* __restrict__ Wd,
                                              f16* __restrict__ W16) {
    int i = blockIdx.x * 256 + threadIdx.x;
    int idx = i * 4;
    int m = idx >> 18;
    int off = idx & 262143;
    const float* src = (m == 0) ? Wb : (m == 1) ? Wc : Wd;
    f32x4 v = *(const f32x4*)(src + off);
    f16x4 h = { (f16)v[0], (f16)v[1], (f16)v[2], (f16)v[3] };
    *(f16x4*)(W16 + idx) = h;
}

// ---------------- proj (all batches): O = W @ x ----------------
__global__ __launch_bounds__(256) void proj_k(const float* __restrict__ x,
                                              const f16* __restrict__ W16,
                                              f16* __restrict__ Bt, f16* __restrict__ Ct,
                                              f16* __restrict__ Dm) {
    const int wsel = blockIdx.z % 3;
    const int b = blockIdx.z / 3;
    const f16* __restrict__ W = W16 + (size_t)wsel * CC * CC;
    const float* __restrict__ X = x + (size_t)b * CC * NN;
    const size_t p16 = (size_t)CC * NN;
    const int o0 = blockIdx.y * 128, n0 = blockIdx.x * 128;

    __shared__ __align__(16) char smraw[34816];
    f16* As = (f16*)smraw;
    f16* Bs = As + 128 * 64;
    f16* T  = (f16*)smraw;

    const int t = threadIdx.x;
    const int wid = t >> 6, lane = t & 63;
    const int wr = wid >> 1, wc = wid & 1;

    f32x4 acc[4][4] = {};
    const int cg = t & 7;
    const int n4 = ((t >> 3) & 31) * 4;

    for (int kc = 0; kc < CC; kc += 64) {
        __syncthreads();
        stage_tile<128>(W + (size_t)o0 * CC + kc, CC, As, wid, lane);
        f32x4 v[8];
        #pragma unroll
        for (int i = 0; i < 8; ++i)
            v[i] = *(const f32x4*)(X + (size_t)(kc + cg * 8 + i) * NN + n0 + n4);
        #pragma unroll
        for (int j = 0; j < 4; ++j) {
            f16x8 h = { (f16)v[0][j], (f16)v[1][j], (f16)v[2][j], (f16)v[3][j],
                        (f16)v[4][j], (f16)v[5][j], (f16)v[6][j], (f16)v[7][j] };
            int r = n4 + j;
            *(f16x8*)(Bs + r * 64 + ((cg ^ (r & 7)) << 3)) = h;
        }
        __syncthreads();
        #pragma unroll
        for (int ks = 0; ks < 2; ++ks) {
            int ch = ks * 4 + (lane >> 4);
            f16x8 a[4], bb[4];
            #pragma unroll
            for (int i = 0; i < 4; ++i) a[i]  = frag_ld(As, wr * 64 + i * 16 + (lane & 15), ch);
            #pragma unroll
            for (int j = 0; j < 4; ++j) bb[j] = frag_ld(Bs, wc * 64 + j * 16 + (lane & 15), ch);
            #pragma unroll
            for (int i = 0; i < 4; ++i)
                #pragma unroll
                for (int j = 0; j < 4; ++j)
                    acc[i][j] = MFMA16(a[i], bb[j], acc[i][j]);
        }
    }

    __syncthreads();
    if (wsel < 2) {
        #pragma unroll
        for (int i = 0; i < 4; ++i)
            #pragma unroll
            for (int j = 0; j < 4; ++j) {
                int n_l = wc * 64 + j * 16 + (lane & 15);
                int o_l = wr * 64 + i * 16 + (lane >> 4) * 4;
                f16x4 h = { (f16)acc[i][j][0], (f16)acc[i][j][1], (f16)acc[i][j][2], (f16)acc[i][j][3] };
                *(f16x4*)(T + n_l * 136 + o_l) = h;
            }
        __syncthreads();
        f16* __restrict__ dst = ((wsel == 0) ? Bt : Ct) + (size_t)b * p16;
        int n = t & 127;
        #pragma unroll
        for (int it = 0; it < 8; ++it) {
            int ch8 = (t >> 7) * 8 + it;
            f16x8 h = *(f16x8*)(T + n * 136 + ch8 * 8);
            *(f16x8*)(dst + (size_t)(n0 + n) * CC + o0 + ch8 * 8) = h;
        }
    } else {
        #pragma unroll
        for (int i = 0; i < 4; ++i)
            #pragma unroll
            for (int j = 0; j < 4; ++j) {
                int n_l = wc * 64 + j * 16 + (lane & 15);
                #pragma unroll
                for (int q = 0; q < 4; ++q) {
                    int o_l = wr * 64 + i * 16 + (lane >> 4) * 4 + q;
                    T[o_l * 136 + n_l] = (f16)acc[i][j][q];
                }
            }
        __syncthreads();
        f16* __restrict__ dst = Dm + (size_t)b * p16;
        int o = t & 127;
        #pragma unroll
        for (int it = 0; it < 8; ++it) {
            int ch8 = (t >> 7) * 8 + it;
            f16x8 h = *(f16x8*)(T + o * 136 + ch8 * 8);
            *(f16x8*)(dst + (size_t)(o0 + o) * NN + n0 + ch8 * 8) = h;
        }
    }
}

// ---------- flash staging helpers ----------
__device__ __forceinline__ void stage_Ct(const f16* __restrict__ Ctb, f16* CtS,
                                         int m0, int wid, int lane) {
    #pragma unroll
    for (int it = 0; it < 8; ++it) {
        int r = wid * 8 + it;
        f16* dst = CtS + r * 512;              // wave-uniform base
        const f16* src = Ctb + (size_t)(m0 + r) * CC + ((lane ^ (r & 7)) << 3);
        gload_lds16(src, dst);
    }
}
__device__ __forceinline__ void stage_Dt(const f16* __restrict__ Dmb, f16* DtS,
                                         int m0, int wid, int lane) {
    #pragma unroll
    for (int it = 0; it < 8; ++it) {
        int flatbase = (wid * 8 + it) * 64;
        f16* dst = DtS + flatbase * 8;
        int flat = flatbase + lane;
        int r = flat >> 3, c = flat & 7;
        const f16* src = Dmb + (size_t)r * NN + m0 + ((c ^ (r & 7)) << 3);
        gload_lds16(src, dst);
    }
}

// ---------------- fused flash attention (reuse-2, register-economized) ----------------
// 8 waves: a = wid>>2 (n-half, 32 rows), mj = wid&3 (m-quarter QK / c-quarter PV).
// Q[2][16]=128v + O[2][8]=64v; softmax fully sequential per f with exp IN PLACE over S
// (no p copies, scl applied immediately) to stay under the 256-reg unified budget
// (512-thread block = 2 waves/SIMD). r5/r6/r8 spilled at ~270 live; this targets ~250.
__global__ __launch_bounds__(512)
void flash_k(
    const float* __restrict__ x, const float* __restrict__ gamma_p,
    const f16* __restrict__ Bt, const f16* __restrict__ Ct,
    const f16* __restrict__ Dm, float* __restrict__ out)
{
    __shared__ __align__(16) char sm[141312];
    f16* CtS = (f16*)sm;                       // [64 m][512 K]   65536 B
    f16* DtS = (f16*)(sm + 65536);             // [512 c][64 m]   65536 B
    f16* PS  = (f16*)(sm + 131072);            // [64 n][64 m]     8192 B
    float* mxp = (float*)(sm + 139264);        // [4 mj][64 n]
    float* lp  = (float*)(sm + 140288);        // [4 mj][64 n]

    // XCD-pair swizzle: 256 blocks
    const int bx = blockIdx.x;
    const int j8 = bx & 7;
    const int b = j8 >> 1;
    const int n0 = ((bx >> 3) + (j8 & 1) * 32) * 64;

    const size_t p16 = (size_t)CC * NN;
    const f16* __restrict__ Btb = Bt + (size_t)b * p16;   // [n][c]
    const f16* __restrict__ Ctb = Ct + (size_t)b * p16;   // [m][c]
    const f16* __restrict__ Dmb = Dm + (size_t)b * p16;   // [c][m]

    const int t = threadIdx.x;
    const int wid = t >> 6, lane = t & 63;
    const int a = wid >> 2, mj = wid & 3;
    const int l15 = lane & 15, g = lane >> 4;
    const int nb = a * 32 + g * 4;              // f=0 row base (f adds 16)

    // Q fragments: Q[f][s] = rows n0 + a*32 + f*16 + l15, K chunk s*32 + g*8
    f16x8 Q[2][16];
    #pragma unroll
    for (int f = 0; f < 2; ++f) {
        const f16* qrow = Btb + (size_t)(n0 + a * 32 + f * 16 + l15) * CC + g * 8;
        #pragma unroll
        for (int s = 0; s < 16; ++s) Q[f][s] = *(const f16x8*)(qrow + s * 32);
    }

    f32x4 O[2][8];
    #pragma unroll
    for (int f = 0; f < 2; ++f)
        #pragma unroll
        for (int j = 0; j < 8; ++j) O[f][j] = (f32x4)(0.f);
    f32x4 m_run[2] = { (f32x4)(-INFINITY), (f32x4)(-INFINITY) };
    f32x4 l_run[2] = { (f32x4)(0.f), (f32x4)(0.f) };

    // prologue
    stage_Ct(Ctb, CtS, 0, wid, lane);
    __syncthreads();

    for (int m0 = 0; m0 < NN; m0 += 64) {
        // Dt(m0) lands under QK, published at bar1
        stage_Dt(Dmb, DtS, m0, wid, lane);

        // QK^T: wave 32n x 16m; each Ct frag feeds 2 MFMAs
        f32x4 S0 = (f32x4)(0.f), S1 = (f32x4)(0.f);
        const int mr = mj * 16 + l15;
        __builtin_amdgcn_s_setprio(1);
        #pragma unroll
        for (int s = 0; s < 16; ++s) {
            f16x8 bfrag = *(const f16x8*)(CtS + mr * 512 + ((((s * 4 + g) ^ (mr & 7)) & 63) << 3));
            S0 = MFMA16(Q[0][s], bfrag, S0);
            S1 = MFMA16(Q[1][s], bfrag, S1);
        }
        __builtin_amdgcn_s_setprio(0);
        {
            f32x4 tm = rmax16(S0);
            if (l15 == 0) *(f32x4*)(mxp + mj * 64 + nb) = tm;
            tm = rmax16(S1);
            if (l15 == 0) *(f32x4*)(mxp + mj * 64 + nb + 16) = tm;
        }
        __syncthreads();                       // bar1: mxp + DtS(m0) published

        // softmax, fully sequential per f (exp in place over S; scl applied now)
        #pragma unroll
        for (int f = 0; f < 2; ++f) {
            f32x4& S = (f == 0) ? S0 : S1;
            const int rb = nb + f * 16;
            #pragma unroll
            for (int q = 0; q < 4; ++q) {
                float mx = fmaxf(fmaxf(mxp[0 * 64 + rb + q - g * 4 + g * 4], mxp[1 * 64 + rb + q]),
                                 fmaxf(mxp[2 * 64 + rb + q], mxp[3 * 64 + rb + q]));
                mx = fmaxf(mxp[0 * 64 + rb + q], mx);   // (ensure c0 included)
                float mnew = fmaxf(m_run[f][q], mx);
                float scl = __expf(m_run[f][q] - mnew);
                m_run[f][q] = mnew;
                S[q] = __expf(S[q] - mnew);
                l_run[f][q] *= scl;
                #pragma unroll
                for (int j = 0; j < 8; ++j) O[f][j][q] *= scl;
            }
            f32x4 ps = rsum16(S);
            if (l15 == 0) *(f32x4*)(lp + mj * 64 + rb) = ps;
            const int mcol = mj * 16 + l15;
            #pragma unroll
            for (int q = 0; q < 4; ++q) {
                int r = rb + q;
                PS[r * 64 + ((((mcol >> 3) ^ (r & 7)) << 3) | (mcol & 7))] = (f16)S[q];
            }
        }
        __syncthreads();                       // bar2: P + lp published

        // Ct(m0+64) lands under PV, published at bar3
        if (m0 + 64 < NN) stage_Ct(Ctb, CtS, m0 + 64, wid, lane);

        #pragma unroll
        for (int f = 0; f < 2; ++f) {
            const int rb = nb + f * 16;
            #pragma unroll
            for (int q = 0; q < 4; ++q)
                l_run[f][q] += ((lp[0 * 64 + rb + q] + lp[1 * 64 + rb + q]) +
                                (lp[2 * 64 + rb + q] + lp[3 * 64 + rb + q]));
        }

        // PV: wave 32n x 128c; each Dt frag feeds 2 MFMAs
        {
            const int r0 = a * 32 + l15, r1 = r0 + 16;
            f16x8 pa00 = *(const f16x8*)(PS + r0 * 64 + (((g ^ (r0 & 7)) & 7) << 3));
            f16x8 pa01 = *(const f16x8*)(PS + r0 * 64 + ((((4 + g) ^ (r0 & 7)) & 7) << 3));
            f16x8 pa10 = *(const f16x8*)(PS + r1 * 64 + (((g ^ (r1 & 7)) & 7) << 3));
            f16x8 pa11 = *(const f16x8*)(PS + r1 * 64 + ((((4 + g) ^ (r1 & 7)) & 7) << 3));
            __builtin_amdgcn_s_setprio(1);
            #pragma unroll
            for (int cf = 0; cf < 8; ++cf) {
                int crow = mj * 128 + cf * 16 + l15;
                f16x8 d0 = *(const f16x8*)(DtS + crow * 64 + (((g ^ (crow & 7)) & 7) << 3));
                f16x8 d1 = *(const f16x8*)(DtS + crow * 64 + ((((4 + g) ^ (crow & 7)) & 7) << 3));
                O[0][cf] = MFMA16(pa00, d0, O[0][cf]);
                O[0][cf] = MFMA16(pa01, d1, O[0][cf]);
                O[1][cf] = MFMA16(pa10, d0, O[1][cf]);
                O[1][cf] = MFMA16(pa11, d1, O[1][cf]);
            }
            __builtin_amdgcn_s_setprio(0);
        }
        __syncthreads();                       // bar3: CtS(next) published; PS consumed
    }

    // ---------------- epilogue: out[c][n] = gamma*O/l + x ----------------
    const float gam = gamma_p[0];
    float* T = (float*)sm;                     // [512][68] f32
    #pragma unroll
    for (int f = 0; f < 2; ++f) {
        f32x4 inv;
        #pragma unroll
        for (int q = 0; q < 4; ++q) inv[q] = gam / l_run[f][q];
        #pragma unroll
        for (int cf = 0; cf < 8; ++cf) {
            int crow = mj * 128 + cf * 16 + l15;
            f32x4 v;
            #pragma unroll
            for (int q = 0; q < 4; ++q) v[q] = O[f][cf][q] * inv[q];
            *(f32x4*)(T + crow * 68 + nb + f * 16) = v;
        }
    }
    __syncthreads();
    const float* __restrict__ xb = x + (size_t)b * CC * NN;
    float* __restrict__ ob = out + (size_t)b * CC * NN;
    #pragma unroll
    for (int it = 0; it < 16; ++it) {
        int c = (t >> 4) + it * 32;
        int n4 = (t & 15) * 4;
        f32x4 v = *(const f32x4*)(T + c * 68 + n4);
        f32x4 xv = *(const f32x4*)(xb + (size_t)c * NN + n0 + n4);
        #pragma unroll
        for (int q = 0; q < 4; ++q) v[q] += xv[q];
        *(f32x4*)(ob + (size_t)c * NN + n0 + n4) = v;
    }
}

extern "C" void kernel_launch(void* const* d_in, const int* in_sizes, int n_in,
                              void* d_out, int out_size, void* d_ws, size_t ws_size,
                              hipStream_t stream) {
    const float* x  = (const float*)d_in[0];
    const float* Wb = (const float*)d_in[1];
    const float* Wc = (const float*)d_in[2];
    const float* Wd = (const float*)d_in[3];
    const float* gm = (const float*)d_in[4];
    float* out = (float*)d_out;
    char* ws = (char*)d_ws;

    // ws: W16 1.5MB | Bt 16MB | Ct 16MB | Dm 16MB  (~49.5MB)
    f16* W16 = (f16*)(ws);
    f16* Bt  = (f16*)(ws + 1572864);
    f16* Ct  = (f16*)(ws + 1572864 + 16777216);
    f16* Dm  = (f16*)(ws + 1572864 + 2 * 16777216);

    wcvt_k<<<dim3(768), 256, 0, stream>>>(Wb, Wc, Wd, W16);
    proj_k<<<dim3(32, 4, 12), 256, 0, stream>>>(x, W16, Bt, Ct, Dm);
    flash_k<<<dim3(256), 512, 0, stream>>>(x, gm, Bt, Ct, Dm, out);
}

// Round 10
// 369.242 us; speedup vs baseline: 3.5812x; 1.9751x over previous
//
#include <hip/hip_runtime.h>
#include <math.h>
#include <stdint.h>

#define CC 512
#define NN 4096
#define BB 4

typedef _Float16 f16;
typedef _Float16 f16x8 __attribute__((ext_vector_type(8)));
typedef _Float16 f16x4 __attribute__((ext_vector_type(4)));
typedef float f32x4 __attribute__((ext_vector_type(4)));

// ---------- async global->LDS 16B ----------
__device__ __forceinline__ void gload_lds16(const void* g, void* l) {
    __builtin_amdgcn_global_load_lds(
        (const __attribute__((address_space(1))) void*)g,
        (__attribute__((address_space(3))) void*)l, 16, 0, 0);
}

// Stage ROWS rows x 64 f16 from K-major global into linear LDS; source pre-swizzled.
template<int ROWS>
__device__ __forceinline__ void stage_tile(const f16* __restrict__ g, int stride_e,
                                           f16* lds, int wid, int lane) {
    constexpr int ITERS = ROWS * 8 / 64 / 4;   // 4 waves
    #pragma unroll
    for (int it = 0; it < ITERS; ++it) {
        int flatbase = (wid * ITERS + it) * 64;
        f16* dst = lds + flatbase * 8;
        int flat = flatbase + lane;
        int r = flat >> 3, c = flat & 7;
        const f16* src = g + (size_t)r * stride_e + ((c ^ (r & 7)) << 3);
        gload_lds16(src, dst);
    }
}

__device__ __forceinline__ f16x8 frag_ld(const f16* lds, int r, int ch) {
    return *(const f16x8*)(lds + r * 64 + ((ch ^ (r & 7)) << 3));
}

#define MFMA16(a, b, c) __builtin_amdgcn_mfma_f32_16x16x32_f16((a), (b), (c), 0, 0, 0)

// ---------- DPP row_ror reductions over 16-lane rows (VALU only) ----------
template<int N>
__device__ __forceinline__ float ror16(float x) {
    return __int_as_float(__builtin_amdgcn_update_dpp(
        0, __float_as_int(x), 0x120 + N, 0xF, 0xF, true));
}
__device__ __forceinline__ f32x4 rmax16(f32x4 v) {
    #pragma unroll
    for (int q = 0; q < 4; ++q) {
        float x = v[q];
        x = fmaxf(x, ror16<1>(x));
        x = fmaxf(x, ror16<2>(x));
        x = fmaxf(x, ror16<4>(x));
        x = fmaxf(x, ror16<8>(x));
        v[q] = x;
    }
    return v;
}
__device__ __forceinline__ f32x4 rsum16(f32x4 v) {
    #pragma unroll
    for (int q = 0; q < 4; ++q) {
        float x = v[q];
        x += ror16<1>(x);
        x += ror16<2>(x);
        x += ror16<4>(x);
        x += ror16<8>(x);
        v[q] = x;
    }
    return v;
}

// ---------------- W conversion ----------------
__global__ __launch_bounds__(256) void wcvt_k(const float* __restrict__ Wb,
                                              const float* __restrict__ Wc,
                                              const float* __restrict__ Wd,
                                              f16* __restrict__ W16) {
    int i = blockIdx.x * 256 + threadIdx.x;
    int idx = i * 4;
    int m = idx >> 18;
    int off = idx & 262143;
    const float* src = (m == 0) ? Wb : (m == 1) ? Wc : Wd;
    f32x4 v = *(const f32x4*)(src + off);
    f16x4 h = { (f16)v[0], (f16)v[1], (f16)v[2], (f16)v[3] };
    *(f16x4*)(W16 + idx) = h;
}

// ---------------- proj (all batches): O = W @ x ----------------
__global__ __launch_bounds__(256) void proj_k(const float* __restrict__ x,
                                              const f16* __restrict__ W16,
                                              f16* __restrict__ Bt, f16* __restrict__ Ct,
                                              f16* __restrict__ Dm) {
    const int wsel = blockIdx.z % 3;
    const int b = blockIdx.z / 3;
    const f16* __restrict__ W = W16 + (size_t)wsel * CC * CC;
    const float* __restrict__ X = x + (size_t)b * CC * NN;
    const size_t p16 = (size_t)CC * NN;
    const int o0 = blockIdx.y * 128, n0 = blockIdx.x * 128;

    __shared__ __align__(16) char smraw[34816];
    f16* As = (f16*)smraw;
    f16* Bs = As + 128 * 64;
    f16* T  = (f16*)smraw;

    const int t = threadIdx.x;
    const int wid = t >> 6, lane = t & 63;
    const int wr = wid >> 1, wc = wid & 1;

    f32x4 acc[4][4] = {};
    const int cg = t & 7;
    const int n4 = ((t >> 3) & 31) * 4;

    for (int kc = 0; kc < CC; kc += 64) {
        __syncthreads();
        stage_tile<128>(W + (size_t)o0 * CC + kc, CC, As, wid, lane);
        f32x4 v[8];
        #pragma unroll
        for (int i = 0; i < 8; ++i)
            v[i] = *(const f32x4*)(X + (size_t)(kc + cg * 8 + i) * NN + n0 + n4);
        #pragma unroll
        for (int j = 0; j < 4; ++j) {
            f16x8 h = { (f16)v[0][j], (f16)v[1][j], (f16)v[2][j], (f16)v[3][j],
                        (f16)v[4][j], (f16)v[5][j], (f16)v[6][j], (f16)v[7][j] };
            int r = n4 + j;
            *(f16x8*)(Bs + r * 64 + ((cg ^ (r & 7)) << 3)) = h;
        }
        __syncthreads();
        #pragma unroll
        for (int ks = 0; ks < 2; ++ks) {
            int ch = ks * 4 + (lane >> 4);
            f16x8 a[4], bb[4];
            #pragma unroll
            for (int i = 0; i < 4; ++i) a[i]  = frag_ld(As, wr * 64 + i * 16 + (lane & 15), ch);
            #pragma unroll
            for (int j = 0; j < 4; ++j) bb[j] = frag_ld(Bs, wc * 64 + j * 16 + (lane & 15), ch);
            #pragma unroll
            for (int i = 0; i < 4; ++i)
                #pragma unroll
                for (int j = 0; j < 4; ++j)
                    acc[i][j] = MFMA16(a[i], bb[j], acc[i][j]);
        }
    }

    __syncthreads();
    if (wsel < 2) {
        #pragma unroll
        for (int i = 0; i < 4; ++i)
            #pragma unroll
            for (int j = 0; j < 4; ++j) {
                int n_l = wc * 64 + j * 16 + (lane & 15);
                int o_l = wr * 64 + i * 16 + (lane >> 4) * 4;
                f16x4 h = { (f16)acc[i][j][0], (f16)acc[i][j][1], (f16)acc[i][j][2], (f16)acc[i][j][3] };
                *(f16x4*)(T + n_l * 136 + o_l) = h;
            }
        __syncthreads();
        f16* __restrict__ dst = ((wsel == 0) ? Bt : Ct) + (size_t)b * p16;
        int n = t & 127;
        #pragma unroll
        for (int it = 0; it < 8; ++it) {
            int ch8 = (t >> 7) * 8 + it;
            f16x8 h = *(f16x8*)(T + n * 136 + ch8 * 8);
            *(f16x8*)(dst + (size_t)(n0 + n) * CC + o0 + ch8 * 8) = h;
        }
    } else {
        #pragma unroll
        for (int i = 0; i < 4; ++i)
            #pragma unroll
            for (int j = 0; j < 4; ++j) {
                int n_l = wc * 64 + j * 16 + (lane & 15);
                #pragma unroll
                for (int q = 0; q < 4; ++q) {
                    int o_l = wr * 64 + i * 16 + (lane >> 4) * 4 + q;
                    T[o_l * 136 + n_l] = (f16)acc[i][j][q];
                }
            }
        __syncthreads();
        f16* __restrict__ dst = Dm + (size_t)b * p16;
        int o = t & 127;
        #pragma unroll
        for (int it = 0; it < 8; ++it) {
            int ch8 = (t >> 7) * 8 + it;
            f16x8 h = *(f16x8*)(T + o * 136 + ch8 * 8);
            *(f16x8*)(dst + (size_t)(o0 + o) * NN + n0 + ch8 * 8) = h;
        }
    }
}

// ---------- flash staging (32-m tiles) ----------
// CtB tile [32 m][512 K], swizzled chunks (ch ^ (r&7)) via pre-swizzled source.
__device__ __forceinline__ void stage_Ct32(const f16* __restrict__ Ctb, f16* dstbase,
                                           int m0, int w4, int lane) {
    #pragma unroll
    for (int it = 0; it < 8; ++it) {
        int flatbase = (w4 * 8 + it) * 64;
        f16* dst = dstbase + flatbase * 8;
        int r = flatbase >> 6;                // uniform: w4*8+it
        const f16* src = Ctb + (size_t)(m0 + r) * CC + ((lane ^ (r & 7)) << 3);
        gload_lds16(src, dst);
    }
}
// DtB tile [512 c][32 m], LINEAR (consecutive-c reads are conflict-free).
// Wave w4 stages exactly rows [w4*128, (w4+1)*128) == the rows it reads in PV.
__device__ __forceinline__ void stage_Dt32(const f16* __restrict__ Dmb, f16* DtB,
                                           int m0, int w4, int lane) {
    #pragma unroll
    for (int it = 0; it < 8; ++it) {
        int flatbase = (w4 * 8 + it) * 64;
        f16* dst = DtB + flatbase * 8;
        int flat = flatbase + lane;
        int r = flat >> 2, c4 = flat & 3;
        const f16* src = Dmb + (size_t)r * NN + m0 + (c4 << 3);
        gload_lds16(src, dst);
    }
}

// ---------------- fused flash attention: producer/consumer gangs ----------------
// 512 thr = 8 waves. Waves 0-3 (producer): QK^T + wave-local softmax for all 64 n
// (16 rows/wave), KVBLK=32. Waves 4-7 (consumer): PV for tile i-1, O = 64n x 128c
// per wave (reuse-4/8 on P/D frags). SIMD k hosts wave k (prod) + wave 4+k (cons)
// -> QK-MFMA, softmax-VALU and PV-MFMA overlap continuously. ONE barrier per iter.
// Q (producer) and O (consumer) share register file R[32] via bit_cast (no union
// allocation -> ~210 regs < 256 budget at 2 waves/SIMD).
__global__ __launch_bounds__(512) void flash_k(
    const float* __restrict__ x, const float* __restrict__ gamma_p,
    const f16* __restrict__ Bt, const f16* __restrict__ Ct,
    const f16* __restrict__ Dm, float* __restrict__ out)
{
    __shared__ __align__(16) char sm[139776];
    f16*   CtB  = (f16*)sm;                    // [2][32][512]  65536 B
    f16*   DtB  = (f16*)(sm + 65536);          // [512][32]     32768 B
    f16*   PSB  = (f16*)(sm + 98304);          // [2][64][32]    8192 B (chunk^g swizzled)
    float* SCL  = (float*)(sm + 106496);       // [2][64]         512 B
    float* LROW = (float*)(sm + 139264);       // [64]            256 B (beyond T)
    // epilogue: T = (float*)sm, [512][68] f32 = 139264 B

    // XCD-pair swizzle: 256 blocks
    const int bx = blockIdx.x;
    const int j8 = bx & 7;
    const int b = j8 >> 1;
    const int n0 = ((bx >> 3) + (j8 & 1) * 32) * 64;

    const size_t p16 = (size_t)CC * NN;
    const f16* __restrict__ Btb = Bt + (size_t)b * p16;   // [n][c]
    const f16* __restrict__ Ctb = Ct + (size_t)b * p16;   // [m][c]
    const f16* __restrict__ Dmb = Dm + (size_t)b * p16;   // [c][m]

    const int t = threadIdx.x;
    const int wid = t >> 6, lane = t & 63;
    const int w4 = wid & 3;
    const bool isP = wid < 4;                  // producer gang
    const int l15 = lane & 15, g = lane >> 4;

    f32x4 R[32];                               // producer: R[0..15] = Q; consumer: O[4][8]
    f32x4 m_run = (f32x4)(-INFINITY);
    f32x4 l_run = (f32x4)(0.f);

    if (isP) {
        const f16* qrow = Btb + (size_t)(n0 + w4 * 16 + l15) * CC + g * 8;
        #pragma unroll
        for (int s = 0; s < 16; ++s)
            R[s] = __builtin_bit_cast(f32x4, *(const f16x8*)(qrow + s * 32));
    } else {
        #pragma unroll
        for (int i = 0; i < 32; ++i) R[i] = (f32x4)(0.f);
    }

    if (isP) stage_Ct32(Ctb, CtB, 0, w4, lane);
    __syncthreads();

    for (int i = 0; i < 128; ++i) {
        const int cur = i & 1;
        if (isP) {
            // prefetch Ct(i+1) into other buffer (lands during this iter)
            if (i + 1 < 128) stage_Ct32(Ctb, CtB + (cur ^ 1) * 16384, (i + 1) * 32, w4, lane);
            // ---- QK(i): 16n x 32m per wave ----
            f32x4 S0 = (f32x4)(0.f), S1 = (f32x4)(0.f);
            const f16* cb = CtB + cur * 16384;
            __builtin_amdgcn_s_setprio(1);
            #pragma unroll
            for (int s = 0; s < 16; ++s) {
                int ch = s * 4 + g;
                f16x8 b0 = *(const f16x8*)(cb + l15 * 512 + ((ch ^ (l15 & 7)) << 3));
                f16x8 b1 = *(const f16x8*)(cb + (16 + l15) * 512 + ((ch ^ (l15 & 7)) << 3));
                f16x8 q = __builtin_bit_cast(f16x8, R[s]);
                S0 = MFMA16(q, b0, S0);
                S1 = MFMA16(q, b1, S1);
            }
            __builtin_amdgcn_s_setprio(0);
            // ---- wave-local softmax (rows w4*16 + g*4 + q) ----
            f32x4 tm, scl;
            #pragma unroll
            for (int q = 0; q < 4; ++q) tm[q] = fmaxf(S0[q], S1[q]);
            tm = rmax16(tm);
            #pragma unroll
            for (int q = 0; q < 4; ++q) {
                float mnew = fmaxf(m_run[q], tm[q]);
                scl[q] = __expf(m_run[q] - mnew);
                m_run[q] = mnew;
                S0[q] = __expf(S0[q] - mnew);
                S1[q] = __expf(S1[q] - mnew);
            }
            f32x4 ps;
            #pragma unroll
            for (int q = 0; q < 4; ++q) ps[q] = S0[q] + S1[q];
            ps = rsum16(ps);
            #pragma unroll
            for (int q = 0; q < 4; ++q) l_run[q] = l_run[q] * scl[q] + ps[q];
            if (l15 == 0) *(f32x4*)(SCL + cur * 64 + w4 * 16 + g * 4) = scl;
            // P write, chunk-swizzled: elem(row,col) at row*32 + ((col>>3 ^ g)<<3) + (col&7)
            f16* pp = PSB + cur * 2048;
            #pragma unroll
            for (int q = 0; q < 4; ++q) {
                int row = w4 * 16 + g * 4 + q;
                pp[row * 32 + ((((l15 >> 3) ^ g) << 3) | (l15 & 7))] = (f16)S0[q];
                pp[row * 32 + ((((2 + (l15 >> 3)) ^ g) << 3) | (l15 & 7))] = (f16)S1[q];
            }
        } else {
            if (i > 0) {
                // ---- PV(i-1): 64n x 128c per wave ----
                const int prev = cur ^ 1;
                const f16* pp = PSB + prev * 2048;
                const float* sc = SCL + prev * 64;
                f32x4 scl4[4];
                #pragma unroll
                for (int na = 0; na < 4; ++na)
                    scl4[na] = *(const f32x4*)(sc + na * 16 + g * 4);
                #pragma unroll
                for (int na = 0; na < 4; ++na)
                    #pragma unroll
                    for (int cb = 0; cb < 8; ++cb)
                        #pragma unroll
                        for (int q = 0; q < 4; ++q)
                            R[na * 8 + cb][q] *= scl4[na][q];
                f16x8 pa[4];
                #pragma unroll
                for (int na = 0; na < 4; ++na) {
                    int row = na * 16 + l15;
                    pa[na] = *(const f16x8*)(pp + row * 32 + ((g ^ (l15 >> 2)) << 3));
                }
                f16x8 d[8];
                #pragma unroll
                for (int cb = 0; cb < 8; ++cb)
                    d[cb] = *(const f16x8*)(DtB + (w4 * 128 + cb * 16 + l15) * 32 + (g << 3));
                __builtin_amdgcn_s_setprio(1);
                #pragma unroll
                for (int na = 0; na < 4; ++na)
                    #pragma unroll
                    for (int cb = 0; cb < 8; ++cb)
                        R[na * 8 + cb] = MFMA16(pa[na], d[cb], R[na * 8 + cb]);
                __builtin_amdgcn_s_setprio(0);
                __builtin_amdgcn_sched_barrier(0);   // keep Dt restage below the reads
            }
            // restage own rows with Dt(i) (consumed at iter i+1)
            stage_Dt32(Dmb, DtB, i * 32, w4, lane);
        }
        __syncthreads();
    }

    // ---- epilogue E1: consumer does PV(127); producer publishes l ----
    if (isP) {
        if (l15 == 0) *(f32x4*)(LROW + w4 * 16 + g * 4) = l_run;
    } else {
        const f16* pp = PSB + 2048;            // prev = 127&1 = 1
        const float* sc = SCL + 64;
        f32x4 scl4[4];
        #pragma unroll
        for (int na = 0; na < 4; ++na)
            scl4[na] = *(const f32x4*)(sc + na * 16 + g * 4);
        #pragma unroll
        for (int na = 0; na < 4; ++na)
            #pragma unroll
            for (int cb = 0; cb < 8; ++cb)
                #pragma unroll
                for (int q = 0; q < 4; ++q)
                    R[na * 8 + cb][q] *= scl4[na][q];
        f16x8 pa[4];
        #pragma unroll
        for (int na = 0; na < 4; ++na) {
            int row = na * 16 + l15;
            pa[na] = *(const f16x8*)(pp + row * 32 + ((g ^ (l15 >> 2)) << 3));
        }
        f16x8 d[8];
        #pragma unroll
        for (int cb = 0; cb < 8; ++cb)
            d[cb] = *(const f16x8*)(DtB + (w4 * 128 + cb * 16 + l15) * 32 + (g << 3));
        #pragma unroll
        for (int na = 0; na < 4; ++na)
            #pragma unroll
            for (int cb = 0; cb < 8; ++cb)
                R[na * 8 + cb] = MFMA16(pa[na], d[cb], R[na * 8 + cb]);
    }
    __syncthreads();

    // ---- E2: consumer writes T[c][n] = gamma * O / l ----
    const float gam = gamma_p[0];
    float* T = (float*)sm;                     // [512][68] f32 (LROW lives beyond)
    if (!isP) {
        #pragma unroll
        for (int na = 0; na < 4; ++na) {
            f32x4 lr = *(const f32x4*)(LROW + na * 16 + g * 4);
            f32x4 inv;
            #pragma unroll
            for (int q = 0; q < 4; ++q) inv[q] = gam / lr[q];
            #pragma unroll
            for (int cb = 0; cb < 8; ++cb) {
                int c = w4 * 128 + cb * 16 + l15;
                f32x4 v;
                #pragma unroll
                for (int q = 0; q < 4; ++q) v[q] = R[na * 8 + cb][q] * inv[q];
                *(f32x4*)(T + c * 68 + na * 16 + g * 4) = v;
            }
        }
    }
    __syncthreads();

    // ---- E3: all threads: out[c][n] = T + x ----
    const float* __restrict__ xb = x + (size_t)b * CC * NN;
    float* __restrict__ ob = out + (size_t)b * CC * NN;
    #pragma unroll
    for (int it = 0; it < 16; ++it) {
        int c = (t >> 4) + it * 32;
        int n4 = (t & 15) * 4;
        f32x4 v = *(const f32x4*)(T + c * 68 + n4);
        f32x4 xv = *(const f32x4*)(xb + (size_t)c * NN + n0 + n4);
        #pragma unroll
        for (int q = 0; q < 4; ++q) v[q] += xv[q];
        *(f32x4*)(ob + (size_t)c * NN + n0 + n4) = v;
    }
}

extern "C" void kernel_launch(void* const* d_in, const int* in_sizes, int n_in,
                              void* d_out, int out_size, void* d_ws, size_t ws_size,
                              hipStream_t stream) {
    const float* x  = (const float*)d_in[0];
    const float* Wb = (const float*)d_in[1];
    const float* Wc = (const float*)d_in[2];
    const float* Wd = (const float*)d_in[3];
    const float* gm = (const float*)d_in[4];
    float* out = (float*)d_out;
    char* ws = (char*)d_ws;

    // ws: W16 1.5MB | Bt 16MB | Ct 16MB | Dm 16MB  (~49.5MB)
    f16* W16 = (f16*)(ws);
    f16* Bt  = (f16*)(ws + 1572864);
    f16* Ct  = (f16*)(ws + 1572864 + 16777216);
    f16* Dm  = (f16*)(ws + 1572864 + 2 * 16777216);

    wcvt_k<<<dim3(768), 256, 0, stream>>>(Wb, Wc, Wd, W16);
    proj_k<<<dim3(32, 4, 12), 256, 0, stream>>>(x, W16, Bt, Ct, Dm);
    flash_k<<<dim3(256), 512, 0, stream>>>(x, gm, Bt, Ct, Dm, out);
}